// Round 13
// baseline (129.105 us; speedup 1.0000x reference)
//
#include <hip/hip_runtime.h>
#include <hip/hip_fp16.h>
#include <stdint.h>
#include <math.h>

#define BB 2
#define TT 2048
#define CC 1024
#define NH 16
#define HD 64
#define N3 (3*CC)
#define NT (TT/64)
#define FFTHR 24.0f     // skip tiles with min FF > 24: rel weight <= ~5e-7

typedef __attribute__((ext_vector_type(8)))  short bf16x8;
typedef __attribute__((ext_vector_type(4)))  float f32x4;
typedef __attribute__((ext_vector_type(16))) float f32x16;

__device__ inline ushort f2bf(float f) {
  uint32_t u = __float_as_uint(f);
  u += 0x7fff + ((u >> 16) & 1);          // RNE
  return (ushort)(u >> 16);
}
__device__ inline uint32_t cvt_pk_bf16(float lo, float hi_) {
  uint32_t r;
  asm("v_cvt_pk_bf16_f32 %0, %1, %2" : "=v"(r) : "v"(lo), "v"(hi_));
  return r;
}
__device__ inline float h2f(ushort u) {
  __half h = *reinterpret_cast<__half*>(&u);
  return __half2float(h);
}
__device__ inline ushort f2h(float f) {
  __half h = __float2half(f);
  return *reinterpret_cast<ushort*>(&h);
}

// direct global -> LDS staging, 16B per lane (dest = wave-uniform base + lane*16)
__device__ inline void gll16(const ushort* g, ushort* l) {
  __builtin_amdgcn_global_load_lds(
      (uint32_t __attribute__((address_space(1)))*)(g),
      (uint32_t __attribute__((address_space(3)))*)(l), 16, 0, 0);
}

typedef union { uint32_t u[4]; bf16x8 v; } pack4_t;

// ---------------- merged cast f32 -> bf16 + minFF init ---------------------
__global__ __launch_bounds__(256) void cast3_k(
    const float* __restrict__ a, const float* __restrict__ b,
    const float* __restrict__ c, ushort* __restrict__ oa,
    ushort* __restrict__ ob, ushort* __restrict__ oc,
    uint32_t* __restrict__ minFFu)
{
  if (blockIdx.x < 8) {                     // init minFF to +inf (8192 uints)
    uint4* p = (uint4*)minFFu;
    p[blockIdx.x*256 + threadIdx.x] = make_uint4(0x7F800000u,0x7F800000u,
                                                 0x7F800000u,0x7F800000u);
  }
  const int n1 = BB*TT*CC, n2 = N3*CC;
  int i = (blockIdx.x * 256 + threadIdx.x) * 4;
  const float* src; ushort* dst;
  if (i < n1)           { src = a + i;            dst = oa + i; }
  else if (i < n1 + n2) { src = b + (i - n1);     dst = ob + (i - n1); }
  else                  { src = c + (i - n1 - n2); dst = oc + (i - n1 - n2); }
  float4 v = *(const float4*)src;
  ushort4 o;
  o.x = f2bf(v.x); o.y = f2bf(v.y); o.z = f2bf(v.z); o.w = f2bf(v.w);
  *(ushort4*)dst = o;
}

// ---------------- bf16 MFMA GEMM: 3-buffer pipeline, stage-after-barrier ---
// STAGE(t+2) issued AFTER the barrier that ends iter t: its loads get a full
// iteration (+barrier) to land, so iter t+1's drain waits on landed loads.
// 1D grid, XCD-swizzled (m204 bijective; requires gridDim.x % 8 == 0).
template<bool OUT_BF16>
__global__ __launch_bounds__(256) void gemm_p3(
    const ushort* __restrict__ A, const ushort* __restrict__ W,
    const float* __restrict__ bias, void* __restrict__ Cout,
    int M, int N, int K)
{
  __shared__ ushort As[3][128*32];
  __shared__ ushort Ws[3][128*32];
  const int tid = threadIdx.x;
  const int lane = tid & 63, wave = tid >> 6;
  const int wr = (wave >> 1) * 64, wc = (wave & 1) * 64;
  const int nbn = N >> 7;
  const int qq = gridDim.x >> 3;
  const int wg = ((int)blockIdx.x & 7) * qq + ((int)blockIdx.x >> 3);
  const int bm = (wg / nbn) * 128, bn = (wg % nbn) * 128;
  const int fr = lane & 15, kg = (lane >> 4) * 8, rg = (lane >> 4) * 4;

  const int srow = wave*32 + (lane >> 2);
  const int scol = (lane & 3) * 8;
  const ushort* ga0 = A + (size_t)(bm + srow) * K + scol;
  const ushort* ga1 = A + (size_t)(bm + srow + 16) * K + scol;
  const ushort* gw0 = W + (size_t)(bn + srow) * K + scol;
  const ushort* gw1 = W + (size_t)(bn + srow + 16) * K + scol;
  const int lb0 = wave*1024, lb1 = wave*1024 + 512;

  f32x4 acc[4][4];
  #pragma unroll
  for (int i=0;i<4;++i)
    #pragma unroll
    for (int j=0;j<4;++j) acc[i][j]=(f32x4){0.f,0.f,0.f,0.f};

  const int nt = K >> 5;
  // prologue: stage tiles 0 and 1
  gll16(ga0,      &As[0][lb0]); gll16(ga1,      &As[0][lb1]);
  gll16(gw0,      &Ws[0][lb0]); gll16(gw1,      &Ws[0][lb1]);
  gll16(ga0 + 32, &As[1][lb0]); gll16(ga1 + 32, &As[1][lb1]);
  gll16(gw0 + 32, &Ws[1][lb0]); gll16(gw1 + 32, &Ws[1][lb1]);
  __syncthreads();

  int cur = 0;
  for (int t = 0; t < nt; ++t) {
    const ushort* as = As[cur];
    const ushort* ws = Ws[cur];
    bf16x8 af[4], wf[4];
    #pragma unroll
    for (int m = 0; m < 4; ++m) af[m] = *(const bf16x8*)&as[(wr + m*16 + fr)*32 + kg];
    #pragma unroll
    for (int n = 0; n < 4; ++n) wf[n] = *(const bf16x8*)&ws[(wc + n*16 + fr)*32 + kg];
    #pragma unroll
    for (int m = 0; m < 4; ++m)
      #pragma unroll
      for (int n = 0; n < 4; ++n)
        acc[m][n] = __builtin_amdgcn_mfma_f32_16x16x32_bf16(af[m], wf[n], acc[m][n], 0, 0, 0);
    __syncthreads();                   // cur reads done; (t+1)-loads drained (old)
    if (t + 2 < nt) {
      const int k2 = (t + 2) * 32;
      int nb = cur + 2; if (nb >= 3) nb -= 3;
      gll16(ga0 + k2, &As[nb][lb0]); gll16(ga1 + k2, &As[nb][lb1]);
      gll16(gw0 + k2, &Ws[nb][lb0]); gll16(gw1 + k2, &Ws[nb][lb1]);
    }
    ++cur; if (cur >= 3) cur -= 3;
  }
  #pragma unroll
  for (int n = 0; n < 4; ++n) {
    const int col = bn + wc + n*16 + fr;
    const float bv = bias[col];
    #pragma unroll
    for (int m = 0; m < 4; ++m)
      #pragma unroll
      for (int r = 0; r < 4; ++r) {
        const int row = bm + wr + m*16 + rg + r;
        const float v = acc[m][n][r] + bv;
        if (OUT_BF16) ((ushort*)Cout)[(size_t)row * N + col] = f2bf(v);
        else          ((float*)Cout)[(size_t)row * N + col]  = v;
      }
  }
}

// ---------------- head-0 scores TRANSPOSED, register-direct ----------------
// ST[b][j][i] = mask(relu(q0.k0/8))^T via swapped 32x32x16 MFMA (A=K, B=Q).
__global__ __launch_bounds__(256) void s_scores_T2(
    const ushort* __restrict__ qkvb, __half* __restrict__ ST)
{
  const int b = blockIdx.y;
  const int l = blockIdx.x;
  int it = (int)((sqrtf(8.f*l + 1.f) - 1.f) * 0.5f);
  while ((it+1)*(it+2)/2 <= l) ++it;
  while (it*(it+1)/2 > l) --it;
  const int jt = l - it*(it+1)/2;            // jt <= it
  const int tid = threadIdx.x, lane = tid & 63, wv = tid >> 6;
  const int hi = lane >> 5, lq = lane & 31;
  const int jsub = wv >> 1, isub = wv & 1;
  if (jt == it && jsub > isub) return;       // j>i everywhere: never read
  const int j0 = jt*64 + jsub*32;
  const int i0 = it*64 + isub*32;
  const ushort* kr = qkvb + (size_t)(b*TT + j0 + lq)*N3 + CC + hi*8;   // K row j
  const ushort* qr = qkvb + (size_t)(b*TT + i0 + lq)*N3 + hi*8;        // Q row i
  f32x16 st;
  #pragma unroll
  for (int r = 0; r < 16; ++r) st[r] = 0.f;
  #pragma unroll
  for (int dc = 0; dc < 4; ++dc) {
    bf16x8 kf = *(const bf16x8*)(kr + dc*16);
    bf16x8 qf = *(const bf16x8*)(qr + dc*16);
    st = __builtin_amdgcn_mfma_f32_32x32x16_bf16(kf, qf, st, 0, 0, 0);
  }
  const int ig = i0 + lq;
  __half* out = ST + (size_t)b*TT*TT + ig;
  #pragma unroll
  for (int r = 0; r < 16; ++r) {
    const int jg = j0 + (r&3) + 8*(r>>2) + 4*hi;
    float v = st[r] * 0.125f;
    v = (jg < ig && jg != 0) ? fmaxf(v, 0.f) : 0.f;   // causal<, col0, diag
    out[(size_t)jg*TT] = __float2half(v);
  }
}

// ---------------- fused exclusive row-scan + minFF atomics -----------------
// FF^T[b][j][i] = sum_{j < i' < i} ST[b][j][i'];  minFF via atomicMin(bits).
__global__ __launch_bounds__(256) void ff_scan(__half* __restrict__ SFH,
                                               uint32_t* __restrict__ minFFu)
{
  const int wv = threadIdx.x >> 6, lane = threadIdx.x & 63;
  const int row = blockIdx.x*4 + wv;
  const int b = row >> 11, jj = row & (TT-1);
  ushort* p = (ushort*)(SFH + ((size_t)b*TT + jj)*TT);
  float acc = 0.f;
  #pragma unroll
  for (int it = 0; it < 4; ++it) {
    const int i0 = it*512 + lane*8;
    bf16x8 raw = *(const bf16x8*)(p + i0);
    float e[8];
    float lsum = 0.f;
    #pragma unroll
    for (int k = 0; k < 8; ++k) {
      const float v = h2f((ushort)raw[k]);
      e[k] = (i0 + k > jj) ? v : 0.f;
      lsum += e[k];
    }
    float sc = lsum;
    #pragma unroll
    for (int off = 1; off < 64; off <<= 1) {
      const float t = __shfl_up(sc, off);
      if (lane >= off) sc += t;
    }
    float pr = acc + (sc - lsum);        // exclusive across lanes = FF^T[jj][i0]
    if ((lane & 3) == 0) {               // i0 multiple of 32: minFF sample point
      const int ib = i0 >> 5;
      atomicMin(&minFFu[(b*64 + (jj >> 5))*64 + ib], __float_as_uint(pr));
    }
    bf16x8 o;
    #pragma unroll
    for (int k = 0; k < 8; ++k) {
      o[k] = (short)f2h(pr);
      pr += e[k];
    }
    *(bf16x8*)(p + i0) = o;
    acc += __shfl(sc, 63);               // wave total
  }
}

// ---------------- flash attention: swapped QK^T, FF-skip, big-first --------
__global__ __launch_bounds__(256) void flash_attn7(
    const ushort* __restrict__ qkvb, const __half* __restrict__ FFT,
    const float* __restrict__ minFF, ushort* __restrict__ Yb)
{
  const int bid = blockIdx.x;
  const int bx = 15 - (bid >> 5);
  const int bh = bid & 31;
  const int b = bh >> 4, h = bh & 15;
  const int tid = threadIdx.x, lane = tid & 63, wv = tid >> 6;
  const int hi = lane >> 5, lq = lane & 31;
  const int i0w = bx*128 + wv*32;
  const int qg  = i0w + lq;
  __shared__ __align__(16) ushort Vt[64][72];
  __shared__ short keep_list[32];
  __shared__ int s_nk;

  const int jtmax = 2*bx + 1;
  const int ibblk = bx*4;
  if (tid < 64) {
    bool kp = false;
    if (tid <= jtmax) {
      const float m0 = minFF[(b*64 + 2*tid)*64 + ibblk];
      const float m1 = minFF[(b*64 + 2*tid + 1)*64 + ibblk];
      kp = fminf(m0, m1) <= FFTHR;
    }
    const unsigned long long mask = __ballot(kp);
    if (tid == 0) {
      int n = 0;
      unsigned long long m = mask;
      while (m) { keep_list[n++] = (short)__builtin_ctzll(m); m &= m - 1; }
      s_nk = n;
    }
  }

  bf16x8 qf[4];
  const ushort* qrow = qkvb + (size_t)(b*TT + qg)*N3 + h*HD + hi*8;
  #pragma unroll
  for (int dc = 0; dc < 4; ++dc) qf[dc] = *(const bf16x8*)(qrow + dc*16);

  f32x16 o0, o1;
  #pragma unroll
  for (int r = 0; r < 16; ++r) { o0[r] = 0.f; o1[r] = 0.f; }
  float m_run = -INFINITY, l_run = 0.f;

  const int vrow = tid & 63, vd = (tid >> 6) * 16;
  const ushort* gv0 = qkvb + (size_t)(b*TT + vrow)*N3 + 2*CC + h*HD + vd;

  __syncthreads();                           // keep_list ready
  const int nk = s_nk;
  bf16x8 u0, u1;
  {
    const size_t off = (size_t)keep_list[0]*64*N3;
    u0 = *(const bf16x8*)(gv0 + off);
    u1 = *(const bf16x8*)(gv0 + off + 8);
  }

  for (int idx = 0; idx < nk; ++idx) {
    const int jt = keep_list[idx];
    const int j0t = jt*64;
    bf16x8 kt[2][4];
    const bool wave_live = (j0t <= i0w + 31);
    if (wave_live) {
      #pragma unroll
      for (int js = 0; js < 2; ++js) {
        const ushort* kr = qkvb + (size_t)(b*TT + j0t + js*32 + lq)*N3 + CC + h*HD + hi*8;
        #pragma unroll
        for (int dc = 0; dc < 4; ++dc) kt[js][dc] = *(const bf16x8*)(kr + dc*16);
      }
    }
    __syncthreads();
    #pragma unroll
    for (int e = 0; e < 8; ++e) {
      Vt[vd + e][vrow]     = (ushort)u0[e];
      Vt[vd + 8 + e][vrow] = (ushort)u1[e];
    }
    __syncthreads();
    if (idx + 1 < nk) {
      const size_t off = (size_t)keep_list[idx+1]*64*N3;
      u0 = *(const bf16x8*)(gv0 + off);
      u1 = *(const bf16x8*)(gv0 + off + 8);
    }
    if (!wave_live) continue;

    #pragma unroll
    for (int jsub = 0; jsub < 2; ++jsub) {
      const int j0s = j0t + jsub*32;
      if (j0s > i0w + 31) continue;
      const float mw = minFF[(b*64 + (j0s >> 5))*64 + (i0w >> 5)];
      if (mw > FFTHR) continue;

      float ffv[16];
      {
        const __half* fft = FFT + (size_t)b*TT*TT + (size_t)j0s*TT + qg;
        #pragma unroll
        for (int r = 0; r < 16; ++r) {
          const int joff = (r&3) + 8*(r>>2) + 4*hi;
          ffv[r] = __half2float(fft[(size_t)joff*TT]);
        }
      }
      f32x16 st;
      #pragma unroll
      for (int r = 0; r < 16; ++r) st[r] = 0.f;
      #pragma unroll
      for (int dc = 0; dc < 4; ++dc)
        st = __builtin_amdgcn_mfma_f32_32x32x16_bf16(kt[jsub][dc], qf[dc], st, 0, 0, 0);

      float lg[16];
      float pmax = -INFINITY;
      const bool need_mask = (j0s + 31 > i0w);
      #pragma unroll
      for (int r = 0; r < 16; ++r) {
        float v = st[r]*0.125f - ffv[r];
        if (need_mask) {
          const int j = j0s + (r&3) + 8*(r>>2) + 4*hi;
          v = (j <= qg) ? v : -INFINITY;
        }
        lg[r] = v;
        pmax = fmaxf(pmax, v);
      }
      pmax = fmaxf(pmax, __shfl_xor(pmax, 32));
      if (!__all(pmax <= m_run)) {           // T13 defer-max
        const float mn = fmaxf(m_run, pmax);
        const float sc = __expf(m_run - mn);
        m_run = mn;
        l_run *= sc;
        #pragma unroll
        for (int r = 0; r < 16; ++r) {
          const float s0 = __shfl(sc, (r&3) + 8*(r>>2) + 4*hi);
          o0[r] *= s0; o1[r] *= s0;
        }
      }
      float rs = 0.f;
      #pragma unroll
      for (int r = 0; r < 16; ++r) {
        const float pe = __expf(lg[r] - m_run);
        lg[r] = pe;
        rs += pe;
      }
      rs += __shfl_xor(rs, 32);
      l_run += rs;
      uint32_t P8[8], Q8[8];
      #pragma unroll
      for (int g = 0; g < 4; ++g) {
        P8[2*g]   = cvt_pk_bf16(lg[4*g],   lg[4*g+1]);
        P8[2*g+1] = cvt_pk_bf16(lg[4*g+2], lg[4*g+3]);
      }
      #pragma unroll
      for (int k = 0; k < 8; ++k) Q8[k] = (uint32_t)__shfl_xor((int)P8[k], 32);
      #pragma unroll
      for (int mm = 0; mm < 2; ++mm) {
        pack4_t pk;
        pk.u[0] = hi ? Q8[4*mm+2] : P8[4*mm];
        pk.u[1] = hi ? Q8[4*mm+3] : P8[4*mm+1];
        pk.u[2] = hi ? P8[4*mm+2] : Q8[4*mm];
        pk.u[3] = hi ? P8[4*mm+3] : Q8[4*mm+1];
        const bf16x8 pa = pk.v;
        const bf16x8 v0 = *(const bf16x8*)&Vt[lq]     [jsub*32 + mm*16 + hi*8];
        const bf16x8 v1 = *(const bf16x8*)&Vt[32 + lq][jsub*32 + mm*16 + hi*8];
        o0 = __builtin_amdgcn_mfma_f32_32x32x16_bf16(pa, v0, o0, 0, 0, 0);
        o1 = __builtin_amdgcn_mfma_f32_32x32x16_bf16(pa, v1, o1, 0, 0, 0);
      }
    }
  }
  const float invl = 1.0f / l_run;
  #pragma unroll
  for (int r = 0; r < 16; ++r) {
    const int qm = (r&3) + 8*(r>>2) + 4*hi;
    const float il = __shfl(invl, qm);
    const size_t row = (size_t)(b*TT + i0w + qm)*CC + h*HD;
    Yb[row + lq]      = f2bf(o0[r] * il);
    Yb[row + 32 + lq] = f2bf(o1[r] * il);
  }
}

// ---------------------------------------------------------------------------
extern "C" void kernel_launch(void* const* d_in, const int* in_sizes, int n_in,
                              void* d_out, int out_size, void* d_ws, size_t ws_size,
                              hipStream_t stream) {
  const float* x      = (const float*)d_in[0];
  const float* w_attn = (const float*)d_in[1];
  const float* b_attn = (const float*)d_in[2];
  const float* w_proj = (const float*)d_in[3];
  const float* b_proj = (const float*)d_in[4];
  float* out = (float*)d_out;

  ushort* xb   = (ushort*)d_ws;                         // B*T*C bf16
  ushort* wab  = xb   + (size_t)BB*TT*CC;               // 3C*C bf16
  ushort* wpb  = wab  + (size_t)N3*CC;                  // C*C bf16
  ushort* qkvb = wpb  + (size_t)CC*CC;                  // B*T*3C bf16
  ushort* Yb   = qkvb + (size_t)BB*TT*N3;               // B*T*C bf16
  __half* SFH  = (__half*)(Yb + (size_t)BB*TT*CC);      // B*T*T fp16 (S^T -> FF^T)
  uint32_t* minFFu = (uint32_t*)(SFH + (size_t)BB*TT*TT); // B*64*64 f32-bits

  const int ntot4 = (BB*TT*CC + N3*CC + CC*CC) / 4;
  cast3_k<<<(ntot4 + 255)/256, 256, 0, stream>>>(x, w_attn, w_proj, xb, wab, wpb,
                                                 minFFu);

  gemm_p3<true><<<(N3/128)*((BB*TT)/128), 256, 0, stream>>>(
      xb, wab, b_attn, (void*)qkvb, BB*TT, N3, CC);

  s_scores_T2<<<dim3((NT*(NT+1))/2, BB), 256, 0, stream>>>(qkvb, SFH);
  ff_scan<<<(BB*TT)/4, 256, 0, stream>>>(SFH, minFFu);

  flash_attn7<<<512, 256, 0, stream>>>(qkvb, SFH, (const float*)minFFu, Yb);

  gemm_p3<false><<<(CC/128)*((BB*TT)/128), 256, 0, stream>>>(
      Yb, wpb, b_proj, (void*)out, BB*TT, CC, CC);
}

// Round 14
// 117.084 us; speedup vs baseline: 1.1027x; 1.1027x over previous
//
#include <hip/hip_runtime.h>
#include <hip/hip_fp16.h>
#include <stdint.h>
#include <math.h>

#define BB 2
#define TT 2048
#define CC 1024
#define NH 16
#define HD 64
#define N3 (3*CC)
#define NT (TT/64)
#define FFTHR 24.0f     // skip tiles with min FF > 24: rel weight <= ~5e-7

typedef __attribute__((ext_vector_type(8)))  short bf16x8;
typedef __attribute__((ext_vector_type(4)))  float f32x4;
typedef __attribute__((ext_vector_type(16))) float f32x16;

__device__ inline ushort f2bf(float f) {
  uint32_t u = __float_as_uint(f);
  u += 0x7fff + ((u >> 16) & 1);          // RNE
  return (ushort)(u >> 16);
}
__device__ inline uint32_t cvt_pk_bf16(float lo, float hi_) {
  uint32_t r;
  asm("v_cvt_pk_bf16_f32 %0, %1, %2" : "=v"(r) : "v"(lo), "v"(hi_));
  return r;
}
__device__ inline float h2f(ushort u) {
  __half h = *reinterpret_cast<__half*>(&u);
  return __half2float(h);
}
__device__ inline ushort f2h(float f) {
  __half h = __float2half(f);
  return *reinterpret_cast<ushort*>(&h);
}

// direct global -> LDS staging, 16B per lane (dest = wave-uniform base + lane*16)
__device__ inline void gll16(const ushort* g, ushort* l) {
  __builtin_amdgcn_global_load_lds(
      (uint32_t __attribute__((address_space(1)))*)(g),
      (uint32_t __attribute__((address_space(3)))*)(l), 16, 0, 0);
}

typedef union { uint32_t u[4]; bf16x8 v; } pack4_t;

// ---------------- merged cast f32 -> bf16 + minFF init ---------------------
__global__ __launch_bounds__(256) void cast3_k(
    const float* __restrict__ a, const float* __restrict__ b,
    const float* __restrict__ c, ushort* __restrict__ oa,
    ushort* __restrict__ ob, ushort* __restrict__ oc,
    uint32_t* __restrict__ minFFu)
{
  if (blockIdx.x < 8) {                     // init minFF to +inf (8192 uints)
    uint4* p = (uint4*)minFFu;
    p[blockIdx.x*256 + threadIdx.x] = make_uint4(0x7F800000u,0x7F800000u,
                                                 0x7F800000u,0x7F800000u);
  }
  const int n1 = BB*TT*CC, n2 = N3*CC;
  int i = (blockIdx.x * 256 + threadIdx.x) * 4;
  const float* src; ushort* dst;
  if (i < n1)           { src = a + i;            dst = oa + i; }
  else if (i < n1 + n2) { src = b + (i - n1);     dst = ob + (i - n1); }
  else                  { src = c + (i - n1 - n2); dst = oc + (i - n1 - n2); }
  float4 v = *(const float4*)src;
  ushort4 o;
  o.x = f2bf(v.x); o.y = f2bf(v.y); o.z = f2bf(v.z); o.w = f2bf(v.w);
  *(ushort4*)dst = o;
}

// ---------------- bf16 MFMA GEMM: 3-buffer, counted-vmcnt pipeline (T4) ----
// Per wave 4 gll16/tile; steady outstanding = 8 (tiles t,t+1).
// s_waitcnt vmcnt(4) waits only tile t's loads; t+1's stay in flight ACROSS
// the raw s_barrier (no vmcnt(0) drain -- the m97-structure stall removed).
template<bool OUT_BF16>
__global__ __launch_bounds__(256) void gemm_cv(
    const ushort* __restrict__ A, const ushort* __restrict__ W,
    const float* __restrict__ bias, void* __restrict__ Cout,
    int M, int N, int K)
{
  __shared__ ushort As[3][128*32];
  __shared__ ushort Ws[3][128*32];
  const int tid = threadIdx.x;
  const int lane = tid & 63, wave = tid >> 6;
  const int wr = (wave >> 1) * 64, wc = (wave & 1) * 64;
  const int nbn = N >> 7;
  const int qq = gridDim.x >> 3;
  const int wg = ((int)blockIdx.x & 7) * qq + ((int)blockIdx.x >> 3);
  const int bm = (wg / nbn) * 128, bn = (wg % nbn) * 128;
  const int fr = lane & 15, kg = (lane >> 4) * 8, rg = (lane >> 4) * 4;

  const int srow = wave*32 + (lane >> 2);
  const int scol = (lane & 3) * 8;
  const ushort* ga0 = A + (size_t)(bm + srow) * K + scol;
  const ushort* ga1 = A + (size_t)(bm + srow + 16) * K + scol;
  const ushort* gw0 = W + (size_t)(bn + srow) * K + scol;
  const ushort* gw1 = W + (size_t)(bn + srow + 16) * K + scol;
  const int lb0 = wave*1024, lb1 = wave*1024 + 512;

  f32x4 acc[4][4];
  #pragma unroll
  for (int i=0;i<4;++i)
    #pragma unroll
    for (int j=0;j<4;++j) acc[i][j]=(f32x4){0.f,0.f,0.f,0.f};

  const int nt = K >> 5;
  // prologue: stage tiles 0 and 1 (8 loads outstanding per wave)
  gll16(ga0,      &As[0][lb0]); gll16(ga1,      &As[0][lb1]);
  gll16(gw0,      &Ws[0][lb0]); gll16(gw1,      &Ws[0][lb1]);
  gll16(ga0 + 32, &As[1][lb0]); gll16(ga1 + 32, &As[1][lb1]);
  gll16(gw0 + 32, &Ws[1][lb0]); gll16(gw1 + 32, &Ws[1][lb1]);

  int cur = 0;
  for (int t = 0; t < nt; ++t) {
    if (t + 1 < nt) asm volatile("s_waitcnt vmcnt(4)" ::: "memory");
    else            asm volatile("s_waitcnt vmcnt(0)" ::: "memory");
    __builtin_amdgcn_s_barrier();          // all waves' tile-t loads landed
    asm volatile("" ::: "memory");         // no LDS-read hoist above barrier
    const ushort* as = As[cur];
    const ushort* ws = Ws[cur];
    bf16x8 af[4], wf[4];
    #pragma unroll
    for (int m = 0; m < 4; ++m) af[m] = *(const bf16x8*)&as[(wr + m*16 + fr)*32 + kg];
    #pragma unroll
    for (int n = 0; n < 4; ++n) wf[n] = *(const bf16x8*)&ws[(wc + n*16 + fr)*32 + kg];
    #pragma unroll
    for (int m = 0; m < 4; ++m)
      #pragma unroll
      for (int n = 0; n < 4; ++n)
        acc[m][n] = __builtin_amdgcn_mfma_f32_16x16x32_bf16(af[m], wf[n], acc[m][n], 0, 0, 0);
    if (t + 2 < nt) {                      // buf[(t+2)%3]==buf[(t-1)%3]: safe,
      const int k2 = (t + 2) * 32;         // all waves past compute(t-1) reads
      int nb = cur + 2; if (nb >= 3) nb -= 3;
      gll16(ga0 + k2, &As[nb][lb0]); gll16(ga1 + k2, &As[nb][lb1]);
      gll16(gw0 + k2, &Ws[nb][lb0]); gll16(gw1 + k2, &Ws[nb][lb1]);
    }
    ++cur; if (cur >= 3) cur -= 3;
  }
  #pragma unroll
  for (int n = 0; n < 4; ++n) {
    const int col = bn + wc + n*16 + fr;
    const float bv = bias[col];
    #pragma unroll
    for (int m = 0; m < 4; ++m)
      #pragma unroll
      for (int r = 0; r < 4; ++r) {
        const int row = bm + wr + m*16 + rg + r;
        const float v = acc[m][n][r] + bv;
        if (OUT_BF16) ((ushort*)Cout)[(size_t)row * N + col] = f2bf(v);
        else          ((float*)Cout)[(size_t)row * N + col]  = v;
      }
  }
}

// ---------------- head-0 scores TRANSPOSED, register-direct ----------------
// ST[b][j][i] = mask(relu(q0.k0/8))^T via swapped 32x32x16 MFMA (A=K, B=Q).
__global__ __launch_bounds__(256) void s_scores_T2(
    const ushort* __restrict__ qkvb, __half* __restrict__ ST)
{
  const int b = blockIdx.y;
  const int l = blockIdx.x;
  int it = (int)((sqrtf(8.f*l + 1.f) - 1.f) * 0.5f);
  while ((it+1)*(it+2)/2 <= l) ++it;
  while (it*(it+1)/2 > l) --it;
  const int jt = l - it*(it+1)/2;            // jt <= it
  const int tid = threadIdx.x, lane = tid & 63, wv = tid >> 6;
  const int hi = lane >> 5, lq = lane & 31;
  const int jsub = wv >> 1, isub = wv & 1;
  if (jt == it && jsub > isub) return;       // j>i everywhere: never read
  const int j0 = jt*64 + jsub*32;
  const int i0 = it*64 + isub*32;
  const ushort* kr = qkvb + (size_t)(b*TT + j0 + lq)*N3 + CC + hi*8;   // K row j
  const ushort* qr = qkvb + (size_t)(b*TT + i0 + lq)*N3 + hi*8;        // Q row i
  f32x16 st;
  #pragma unroll
  for (int r = 0; r < 16; ++r) st[r] = 0.f;
  #pragma unroll
  for (int dc = 0; dc < 4; ++dc) {
    bf16x8 kf = *(const bf16x8*)(kr + dc*16);
    bf16x8 qf = *(const bf16x8*)(qr + dc*16);
    st = __builtin_amdgcn_mfma_f32_32x32x16_bf16(kf, qf, st, 0, 0, 0);
  }
  const int ig = i0 + lq;
  __half* out = ST + (size_t)b*TT*TT + ig;
  #pragma unroll
  for (int r = 0; r < 16; ++r) {
    const int jg = j0 + (r&3) + 8*(r>>2) + 4*hi;
    float v = st[r] * 0.125f;
    v = (jg < ig && jg != 0) ? fmaxf(v, 0.f) : 0.f;   // causal<, col0, diag
    out[(size_t)jg*TT] = __float2half(v);
  }
}

// ---------------- fused exclusive row-scan + minFF atomics -----------------
// FF^T[b][j][i] = sum_{j < i' < i} ST[b][j][i'];  minFF via atomicMin(bits).
__global__ __launch_bounds__(256) void ff_scan(__half* __restrict__ SFH,
                                               uint32_t* __restrict__ minFFu)
{
  const int wv = threadIdx.x >> 6, lane = threadIdx.x & 63;
  const int row = blockIdx.x*4 + wv;
  const int b = row >> 11, jj = row & (TT-1);
  ushort* p = (ushort*)(SFH + ((size_t)b*TT + jj)*TT);
  float acc = 0.f;
  #pragma unroll
  for (int it = 0; it < 4; ++it) {
    const int i0 = it*512 + lane*8;
    bf16x8 raw = *(const bf16x8*)(p + i0);
    float e[8];
    float lsum = 0.f;
    #pragma unroll
    for (int k = 0; k < 8; ++k) {
      const float v = h2f((ushort)raw[k]);
      e[k] = (i0 + k > jj) ? v : 0.f;
      lsum += e[k];
    }
    float sc = lsum;
    #pragma unroll
    for (int off = 1; off < 64; off <<= 1) {
      const float t = __shfl_up(sc, off);
      if (lane >= off) sc += t;
    }
    float pr = acc + (sc - lsum);        // exclusive across lanes = FF^T[jj][i0]
    if ((lane & 3) == 0) {               // i0 multiple of 32: minFF sample point
      const int ib = i0 >> 5;
      atomicMin(&minFFu[(b*64 + (jj >> 5))*64 + ib], __float_as_uint(pr));
    }
    bf16x8 o;
    #pragma unroll
    for (int k = 0; k < 8; ++k) {
      o[k] = (short)f2h(pr);
      pr += e[k];
    }
    *(bf16x8*)(p + i0) = o;
    acc += __shfl(sc, 63);               // wave total
  }
}

// ---------------- flash attention: swapped QK^T, FF-skip, big-first --------
__global__ __launch_bounds__(256) void flash_attn7(
    const ushort* __restrict__ qkvb, const __half* __restrict__ FFT,
    const float* __restrict__ minFF, ushort* __restrict__ Yb)
{
  const int bid = blockIdx.x;
  const int bx = 15 - (bid >> 5);
  const int bh = bid & 31;
  const int b = bh >> 4, h = bh & 15;
  const int tid = threadIdx.x, lane = tid & 63, wv = tid >> 6;
  const int hi = lane >> 5, lq = lane & 31;
  const int i0w = bx*128 + wv*32;
  const int qg  = i0w + lq;
  __shared__ __align__(16) ushort Vt[64][72];
  __shared__ short keep_list[32];
  __shared__ int s_nk;

  const int jtmax = 2*bx + 1;
  const int ibblk = bx*4;
  if (tid < 64) {
    bool kp = false;
    if (tid <= jtmax) {
      const float m0 = minFF[(b*64 + 2*tid)*64 + ibblk];
      const float m1 = minFF[(b*64 + 2*tid + 1)*64 + ibblk];
      kp = fminf(m0, m1) <= FFTHR;
    }
    const unsigned long long mask = __ballot(kp);
    if (tid == 0) {
      int n = 0;
      unsigned long long m = mask;
      while (m) { keep_list[n++] = (short)__builtin_ctzll(m); m &= m - 1; }
      s_nk = n;
    }
  }

  bf16x8 qf[4];
  const ushort* qrow = qkvb + (size_t)(b*TT + qg)*N3 + h*HD + hi*8;
  #pragma unroll
  for (int dc = 0; dc < 4; ++dc) qf[dc] = *(const bf16x8*)(qrow + dc*16);

  f32x16 o0, o1;
  #pragma unroll
  for (int r = 0; r < 16; ++r) { o0[r] = 0.f; o1[r] = 0.f; }
  float m_run = -INFINITY, l_run = 0.f;

  const int vrow = tid & 63, vd = (tid >> 6) * 16;
  const ushort* gv0 = qkvb + (size_t)(b*TT + vrow)*N3 + 2*CC + h*HD + vd;

  __syncthreads();                           // keep_list ready
  const int nk = s_nk;
  bf16x8 u0, u1;
  {
    const size_t off = (size_t)keep_list[0]*64*N3;
    u0 = *(const bf16x8*)(gv0 + off);
    u1 = *(const bf16x8*)(gv0 + off + 8);
  }

  for (int idx = 0; idx < nk; ++idx) {
    const int jt = keep_list[idx];
    const int j0t = jt*64;
    bf16x8 kt[2][4];
    const bool wave_live = (j0t <= i0w + 31);
    if (wave_live) {
      #pragma unroll
      for (int js = 0; js < 2; ++js) {
        const ushort* kr = qkvb + (size_t)(b*TT + j0t + js*32 + lq)*N3 + CC + h*HD + hi*8;
        #pragma unroll
        for (int dc = 0; dc < 4; ++dc) kt[js][dc] = *(const bf16x8*)(kr + dc*16);
      }
    }
    __syncthreads();
    #pragma unroll
    for (int e = 0; e < 8; ++e) {
      Vt[vd + e][vrow]     = (ushort)u0[e];
      Vt[vd + 8 + e][vrow] = (ushort)u1[e];
    }
    __syncthreads();
    if (idx + 1 < nk) {
      const size_t off = (size_t)keep_list[idx+1]*64*N3;
      u0 = *(const bf16x8*)(gv0 + off);
      u1 = *(const bf16x8*)(gv0 + off + 8);
    }
    if (!wave_live) continue;

    #pragma unroll
    for (int jsub = 0; jsub < 2; ++jsub) {
      const int j0s = j0t + jsub*32;
      if (j0s > i0w + 31) continue;
      const float mw = minFF[(b*64 + (j0s >> 5))*64 + (i0w >> 5)];
      if (mw > FFTHR) continue;

      float ffv[16];
      {
        const __half* fft = FFT + (size_t)b*TT*TT + (size_t)j0s*TT + qg;
        #pragma unroll
        for (int r = 0; r < 16; ++r) {
          const int joff = (r&3) + 8*(r>>2) + 4*hi;
          ffv[r] = __half2float(fft[(size_t)joff*TT]);
        }
      }
      f32x16 st;
      #pragma unroll
      for (int r = 0; r < 16; ++r) st[r] = 0.f;
      #pragma unroll
      for (int dc = 0; dc < 4; ++dc)
        st = __builtin_amdgcn_mfma_f32_32x32x16_bf16(kt[jsub][dc], qf[dc], st, 0, 0, 0);

      float lg[16];
      float pmax = -INFINITY;
      const bool need_mask = (j0s + 31 > i0w);
      #pragma unroll
      for (int r = 0; r < 16; ++r) {
        float v = st[r]*0.125f - ffv[r];
        if (need_mask) {
          const int j = j0s + (r&3) + 8*(r>>2) + 4*hi;
          v = (j <= qg) ? v : -INFINITY;
        }
        lg[r] = v;
        pmax = fmaxf(pmax, v);
      }
      pmax = fmaxf(pmax, __shfl_xor(pmax, 32));
      if (!__all(pmax <= m_run)) {           // T13 defer-max
        const float mn = fmaxf(m_run, pmax);
        const float sc = __expf(m_run - mn);
        m_run = mn;
        l_run *= sc;
        #pragma unroll
        for (int r = 0; r < 16; ++r) {
          const float s0 = __shfl(sc, (r&3) + 8*(r>>2) + 4*hi);
          o0[r] *= s0; o1[r] *= s0;
        }
      }
      float rs = 0.f;
      #pragma unroll
      for (int r = 0; r < 16; ++r) {
        const float pe = __expf(lg[r] - m_run);
        lg[r] = pe;
        rs += pe;
      }
      rs += __shfl_xor(rs, 32);
      l_run += rs;
      uint32_t P8[8], Q8[8];
      #pragma unroll
      for (int g = 0; g < 4; ++g) {
        P8[2*g]   = cvt_pk_bf16(lg[4*g],   lg[4*g+1]);
        P8[2*g+1] = cvt_pk_bf16(lg[4*g+2], lg[4*g+3]);
      }
      #pragma unroll
      for (int k = 0; k < 8; ++k) Q8[k] = (uint32_t)__shfl_xor((int)P8[k], 32);
      #pragma unroll
      for (int mm = 0; mm < 2; ++mm) {
        pack4_t pk;
        pk.u[0] = hi ? Q8[4*mm+2] : P8[4*mm];
        pk.u[1] = hi ? Q8[4*mm+3] : P8[4*mm+1];
        pk.u[2] = hi ? P8[4*mm+2] : Q8[4*mm];
        pk.u[3] = hi ? P8[4*mm+3] : Q8[4*mm+1];
        const bf16x8 pa = pk.v;
        const bf16x8 v0 = *(const bf16x8*)&Vt[lq]     [jsub*32 + mm*16 + hi*8];
        const bf16x8 v1 = *(const bf16x8*)&Vt[32 + lq][jsub*32 + mm*16 + hi*8];
        o0 = __builtin_amdgcn_mfma_f32_32x32x16_bf16(pa, v0, o0, 0, 0, 0);
        o1 = __builtin_amdgcn_mfma_f32_32x32x16_bf16(pa, v1, o1, 0, 0, 0);
      }
    }
  }
  const float invl = 1.0f / l_run;
  #pragma unroll
  for (int r = 0; r < 16; ++r) {
    const int qm = (r&3) + 8*(r>>2) + 4*hi;
    const float il = __shfl(invl, qm);
    const size_t row = (size_t)(b*TT + i0w + qm)*CC + h*HD;
    Yb[row + lq]      = f2bf(o0[r] * il);
    Yb[row + 32 + lq] = f2bf(o1[r] * il);
  }
}

// ---------------------------------------------------------------------------
extern "C" void kernel_launch(void* const* d_in, const int* in_sizes, int n_in,
                              void* d_out, int out_size, void* d_ws, size_t ws_size,
                              hipStream_t stream) {
  const float* x      = (const float*)d_in[0];
  const float* w_attn = (const float*)d_in[1];
  const float* b_attn = (const float*)d_in[2];
  const float* w_proj = (const float*)d_in[3];
  const float* b_proj = (const float*)d_in[4];
  float* out = (float*)d_out;

  ushort* xb   = (ushort*)d_ws;                         // B*T*C bf16
  ushort* wab  = xb   + (size_t)BB*TT*CC;               // 3C*C bf16
  ushort* wpb  = wab  + (size_t)N3*CC;                  // C*C bf16
  ushort* qkvb = wpb  + (size_t)CC*CC;                  // B*T*3C bf16
  ushort* Yb   = qkvb + (size_t)BB*TT*N3;               // B*T*C bf16
  __half* SFH  = (__half*)(Yb + (size_t)BB*TT*CC);      // B*T*T fp16 (S^T -> FF^T)
  uint32_t* minFFu = (uint32_t*)(SFH + (size_t)BB*TT*TT); // B*64*64 f32-bits

  const int ntot4 = (BB*TT*CC + N3*CC + CC*CC) / 4;
  cast3_k<<<(ntot4 + 255)/256, 256, 0, stream>>>(x, w_attn, w_proj, xb, wab, wpb,
                                                 minFFu);

  gemm_cv<true><<<(N3/128)*((BB*TT)/128), 256, 0, stream>>>(
      xb, wab, b_attn, (void*)qkvb, BB*TT, N3, CC);

  s_scores_T2<<<dim3((NT*(NT+1))/2, BB), 256, 0, stream>>>(qkvb, SFH);
  ff_scan<<<(BB*TT)/4, 256, 0, stream>>>(SFH, minFFu);

  flash_attn7<<<512, 256, 0, stream>>>(qkvb, SFH, (const float*)minFFu, Yb);

  gemm_cv<false><<<(CC/128)*((BB*TT)/128), 256, 0, stream>>>(
      Yb, wpb, b_proj, (void*)out, BB*TT, CC, CC);
}

// Round 15
// 113.142 us; speedup vs baseline: 1.1411x; 1.0348x over previous
//
#include <hip/hip_runtime.h>
#include <hip/hip_fp16.h>
#include <stdint.h>
#include <math.h>

#define BB 2
#define TT 2048
#define CC 1024
#define NH 16
#define HD 64
#define N3 (3*CC)
#define NT (TT/64)
#define FFTHR 18.0f     // skip tiles with min FF > 18: rel mass <= ~2048 e^-12

typedef __attribute__((ext_vector_type(8)))  short bf16x8;
typedef __attribute__((ext_vector_type(4)))  float f32x4;
typedef __attribute__((ext_vector_type(16))) float f32x16;

__device__ inline ushort f2bf(float f) {
  uint32_t u = __float_as_uint(f);
  u += 0x7fff + ((u >> 16) & 1);          // RNE
  return (ushort)(u >> 16);
}
__device__ inline uint32_t cvt_pk_bf16(float lo, float hi_) {
  uint32_t r;
  asm("v_cvt_pk_bf16_f32 %0, %1, %2" : "=v"(r) : "v"(lo), "v"(hi_));
  return r;
}
__device__ inline float h2f(ushort u) {
  __half h = *reinterpret_cast<__half*>(&u);
  return __half2float(h);
}
__device__ inline ushort f2h(float f) {
  __half h = __float2half(f);
  return *reinterpret_cast<ushort*>(&h);
}

// direct global -> LDS staging, 16B per lane (dest = wave-uniform base + lane*16)
__device__ inline void gll16(const ushort* g, ushort* l) {
  __builtin_amdgcn_global_load_lds(
      (uint32_t __attribute__((address_space(1)))*)(g),
      (uint32_t __attribute__((address_space(3)))*)(l), 16, 0, 0);
}

typedef union { uint32_t u[4]; bf16x8 v; } pack4_t;

// ---------------- merged cast f32 -> bf16 + minFF init ---------------------
__global__ __launch_bounds__(256) void cast3_k(
    const float* __restrict__ a, const float* __restrict__ b,
    const float* __restrict__ c, ushort* __restrict__ oa,
    ushort* __restrict__ ob, ushort* __restrict__ oc,
    uint32_t* __restrict__ minFFu)
{
  if (blockIdx.x < 8) {                     // init minFF to +inf (8192 uints)
    uint4* p = (uint4*)minFFu;
    p[blockIdx.x*256 + threadIdx.x] = make_uint4(0x7F800000u,0x7F800000u,
                                                 0x7F800000u,0x7F800000u);
  }
  const int n1 = BB*TT*CC, n2 = N3*CC;
  int i = (blockIdx.x * 256 + threadIdx.x) * 4;
  const float* src; ushort* dst;
  if (i < n1)           { src = a + i;            dst = oa + i; }
  else if (i < n1 + n2) { src = b + (i - n1);     dst = ob + (i - n1); }
  else                  { src = c + (i - n1 - n2); dst = oc + (i - n1 - n2); }
  float4 v = *(const float4*)src;
  ushort4 o;
  o.x = f2bf(v.x); o.y = f2bf(v.y); o.z = f2bf(v.z); o.w = f2bf(v.w);
  *(ushort4*)dst = o;
}

// ---------------- bf16 MFMA GEMM: 3-buffer counted-vmcnt + LDS swizzle -----
// Swizzle (rule 21 both-sides): phys 16B-slot = (row*4 + kslot) ^ (row & 7).
// gll16 writes lane->slot linearly, so the GLOBAL source is lane-permuted
// (inverse bijection) and frag reads XOR the slot index. 8-way -> 2-way.
template<bool OUT_BF16>
__global__ __launch_bounds__(256) void gemm_sw(
    const ushort* __restrict__ A, const ushort* __restrict__ W,
    const float* __restrict__ bias, void* __restrict__ Cout,
    int M, int N, int K)
{
  __shared__ ushort As[3][128*32];
  __shared__ ushort Ws[3][128*32];
  const int tid = threadIdx.x;
  const int lane = tid & 63, wave = tid >> 6;
  const int wr = (wave >> 1) * 64, wc = (wave & 1) * 64;
  const int nbn = N >> 7;
  const int qq = gridDim.x >> 3;
  const int wg = ((int)blockIdx.x & 7) * qq + ((int)blockIdx.x >> 3);
  const int bm = (wg / nbn) * 128, bn = (wg % nbn) * 128;
  const int fr = lane & 15, rg = (lane >> 4) * 4;
  const int kslot = lane >> 4;

  // inverse slot permutation: lane l stages the data of logical slot sl
  const int sl = (lane & 0x38)
               | ((((lane>>2) ^ (lane>>4)) & 1) << 2)
               | ((((lane>>1) ^ (lane>>3)) & 1) << 1)
               | ((lane ^ (lane>>2) ^ (lane>>4)) & 1);
  const int srow = wave*32 + (sl >> 2);
  const int scol = (sl & 3) * 8;
  const ushort* ga0 = A + (size_t)(bm + srow) * K + scol;
  const ushort* ga1 = A + (size_t)(bm + srow + 16) * K + scol;
  const ushort* gw0 = W + (size_t)(bn + srow) * K + scol;
  const ushort* gw1 = W + (size_t)(bn + srow + 16) * K + scol;
  const int lb0 = wave*1024, lb1 = wave*1024 + 512;

  f32x4 acc[4][4];
  #pragma unroll
  for (int i=0;i<4;++i)
    #pragma unroll
    for (int j=0;j<4;++j) acc[i][j]=(f32x4){0.f,0.f,0.f,0.f};

  const int nt = K >> 5;
  // prologue: stage tiles 0 and 1 (8 loads outstanding per wave)
  gll16(ga0,      &As[0][lb0]); gll16(ga1,      &As[0][lb1]);
  gll16(gw0,      &Ws[0][lb0]); gll16(gw1,      &Ws[0][lb1]);
  gll16(ga0 + 32, &As[1][lb0]); gll16(ga1 + 32, &As[1][lb1]);
  gll16(gw0 + 32, &Ws[1][lb0]); gll16(gw1 + 32, &Ws[1][lb1]);

  int cur = 0;
  for (int t = 0; t < nt; ++t) {
    if (t + 1 < nt) asm volatile("s_waitcnt vmcnt(4)" ::: "memory");
    else            asm volatile("s_waitcnt vmcnt(0)" ::: "memory");
    __builtin_amdgcn_s_barrier();          // all waves' tile-t loads landed
    asm volatile("" ::: "memory");         // no LDS-read hoist above barrier
    const ushort* as = As[cur];
    const ushort* ws = Ws[cur];
    bf16x8 af[4], wf[4];
    #pragma unroll
    for (int m = 0; m < 4; ++m) {
      const int row = wr + m*16 + fr;
      af[m] = *(const bf16x8*)&as[((((row<<2) + kslot) ^ (row & 7)) << 3)];
    }
    #pragma unroll
    for (int n = 0; n < 4; ++n) {
      const int row = wc + n*16 + fr;
      wf[n] = *(const bf16x8*)&ws[((((row<<2) + kslot) ^ (row & 7)) << 3)];
    }
    #pragma unroll
    for (int m = 0; m < 4; ++m)
      #pragma unroll
      for (int n = 0; n < 4; ++n)
        acc[m][n] = __builtin_amdgcn_mfma_f32_16x16x32_bf16(af[m], wf[n], acc[m][n], 0, 0, 0);
    if (t + 2 < nt) {                      // buf[(t+2)%3]==buf[(t-1)%3]: safe
      const int k2 = (t + 2) * 32;
      int nb = cur + 2; if (nb >= 3) nb -= 3;
      gll16(ga0 + k2, &As[nb][lb0]); gll16(ga1 + k2, &As[nb][lb1]);
      gll16(gw0 + k2, &Ws[nb][lb0]); gll16(gw1 + k2, &Ws[nb][lb1]);
    }
    ++cur; if (cur >= 3) cur -= 3;
  }
  #pragma unroll
  for (int n = 0; n < 4; ++n) {
    const int col = bn + wc + n*16 + fr;
    const float bv = bias[col];
    #pragma unroll
    for (int m = 0; m < 4; ++m)
      #pragma unroll
      for (int r = 0; r < 4; ++r) {
        const int row = bm + wr + m*16 + rg + r;
        const float v = acc[m][n][r] + bv;
        if (OUT_BF16) ((ushort*)Cout)[(size_t)row * N + col] = f2bf(v);
        else          ((float*)Cout)[(size_t)row * N + col]  = v;
      }
  }
}

// ---------------- head-0 scores TRANSPOSED, register-direct ----------------
// ST[b][j][i] = mask(relu(q0.k0/8))^T via swapped 32x32x16 MFMA (A=K, B=Q).
__global__ __launch_bounds__(256) void s_scores_T2(
    const ushort* __restrict__ qkvb, __half* __restrict__ ST)
{
  const int b = blockIdx.y;
  const int l = blockIdx.x;
  int it = (int)((sqrtf(8.f*l + 1.f) - 1.f) * 0.5f);
  while ((it+1)*(it+2)/2 <= l) ++it;
  while (it*(it+1)/2 > l) --it;
  const int jt = l - it*(it+1)/2;            // jt <= it
  const int tid = threadIdx.x, lane = tid & 63, wv = tid >> 6;
  const int hi = lane >> 5, lq = lane & 31;
  const int jsub = wv >> 1, isub = wv & 1;
  if (jt == it && jsub > isub) return;       // j>i everywhere: never read
  const int j0 = jt*64 + jsub*32;
  const int i0 = it*64 + isub*32;
  const ushort* kr = qkvb + (size_t)(b*TT + j0 + lq)*N3 + CC + hi*8;   // K row j
  const ushort* qr = qkvb + (size_t)(b*TT + i0 + lq)*N3 + hi*8;        // Q row i
  f32x16 st;
  #pragma unroll
  for (int r = 0; r < 16; ++r) st[r] = 0.f;
  #pragma unroll
  for (int dc = 0; dc < 4; ++dc) {
    bf16x8 kf = *(const bf16x8*)(kr + dc*16);
    bf16x8 qf = *(const bf16x8*)(qr + dc*16);
    st = __builtin_amdgcn_mfma_f32_32x32x16_bf16(kf, qf, st, 0, 0, 0);
  }
  const int ig = i0 + lq;
  __half* out = ST + (size_t)b*TT*TT + ig;
  #pragma unroll
  for (int r = 0; r < 16; ++r) {
    const int jg = j0 + (r&3) + 8*(r>>2) + 4*hi;
    float v = st[r] * 0.125f;
    v = (jg < ig && jg != 0) ? fmaxf(v, 0.f) : 0.f;   // causal<, col0, diag
    out[(size_t)jg*TT] = __float2half(v);
  }
}

// ---------------- fused exclusive row-scan + minFF atomics -----------------
// FF^T[b][j][i] = sum_{j < i' < i} ST[b][j][i'];  minFF via atomicMin(bits).
__global__ __launch_bounds__(256) void ff_scan(__half* __restrict__ SFH,
                                               uint32_t* __restrict__ minFFu)
{
  const int wv = threadIdx.x >> 6, lane = threadIdx.x & 63;
  const int row = blockIdx.x*4 + wv;
  const int b = row >> 11, jj = row & (TT-1);
  ushort* p = (ushort*)(SFH + ((size_t)b*TT + jj)*TT);
  float acc = 0.f;
  #pragma unroll
  for (int it = 0; it < 4; ++it) {
    const int i0 = it*512 + lane*8;
    bf16x8 raw = *(const bf16x8*)(p + i0);
    float e[8];
    float lsum = 0.f;
    #pragma unroll
    for (int k = 0; k < 8; ++k) {
      const float v = h2f((ushort)raw[k]);
      e[k] = (i0 + k > jj) ? v : 0.f;
      lsum += e[k];
    }
    float sc = lsum;
    #pragma unroll
    for (int off = 1; off < 64; off <<= 1) {
      const float t = __shfl_up(sc, off);
      if (lane >= off) sc += t;
    }
    float pr = acc + (sc - lsum);        // exclusive across lanes = FF^T[jj][i0]
    if ((lane & 3) == 0) {               // i0 multiple of 32: minFF sample point
      const int ib = i0 >> 5;
      atomicMin(&minFFu[(b*64 + (jj >> 5))*64 + ib], __float_as_uint(pr));
    }
    bf16x8 o;
    #pragma unroll
    for (int k = 0; k < 8; ++k) {
      o[k] = (short)f2h(pr);
      pr += e[k];
    }
    *(bf16x8*)(p + i0) = o;
    acc += __shfl(sc, 63);               // wave total
  }
}

// ---------------- flash attention: swapped QK^T, FF-skip, big-first --------
__global__ __launch_bounds__(256) void flash_attn7(
    const ushort* __restrict__ qkvb, const __half* __restrict__ FFT,
    const float* __restrict__ minFF, ushort* __restrict__ Yb)
{
  const int bid = blockIdx.x;
  const int bx = 15 - (bid >> 5);
  const int bh = bid & 31;
  const int b = bh >> 4, h = bh & 15;
  const int tid = threadIdx.x, lane = tid & 63, wv = tid >> 6;
  const int hi = lane >> 5, lq = lane & 31;
  const int i0w = bx*128 + wv*32;
  const int qg  = i0w + lq;
  __shared__ __align__(16) ushort Vt[64][72];
  __shared__ short keep_list[32];
  __shared__ int s_nk;

  const int jtmax = 2*bx + 1;
  const int ibblk = bx*4;
  if (tid < 64) {
    bool kp = false;
    if (tid <= jtmax) {
      const float m0 = minFF[(b*64 + 2*tid)*64 + ibblk];
      const float m1 = minFF[(b*64 + 2*tid + 1)*64 + ibblk];
      kp = fminf(m0, m1) <= FFTHR;
    }
    const unsigned long long mask = __ballot(kp);
    if (tid == 0) {
      int n = 0;
      unsigned long long m = mask;
      while (m) { keep_list[n++] = (short)__builtin_ctzll(m); m &= m - 1; }
      s_nk = n;
    }
  }

  bf16x8 qf[4];
  const ushort* qrow = qkvb + (size_t)(b*TT + qg)*N3 + h*HD + hi*8;
  #pragma unroll
  for (int dc = 0; dc < 4; ++dc) qf[dc] = *(const bf16x8*)(qrow + dc*16);

  f32x16 o0, o1;
  #pragma unroll
  for (int r = 0; r < 16; ++r) { o0[r] = 0.f; o1[r] = 0.f; }
  float m_run = -INFINITY, l_run = 0.f;

  const int vrow = tid & 63, vd = (tid >> 6) * 16;
  const ushort* gv0 = qkvb + (size_t)(b*TT + vrow)*N3 + 2*CC + h*HD + vd;

  __syncthreads();                           // keep_list ready
  const int nk = s_nk;
  bf16x8 u0, u1;
  {
    const size_t off = (size_t)keep_list[0]*64*N3;
    u0 = *(const bf16x8*)(gv0 + off);
    u1 = *(const bf16x8*)(gv0 + off + 8);
  }

  for (int idx = 0; idx < nk; ++idx) {
    const int jt = keep_list[idx];
    const int j0t = jt*64;
    bf16x8 kt[2][4];
    const bool wave_live = (j0t <= i0w + 31);
    if (wave_live) {
      #pragma unroll
      for (int js = 0; js < 2; ++js) {
        const ushort* kr = qkvb + (size_t)(b*TT + j0t + js*32 + lq)*N3 + CC + h*HD + hi*8;
        #pragma unroll
        for (int dc = 0; dc < 4; ++dc) kt[js][dc] = *(const bf16x8*)(kr + dc*16);
      }
    }
    __syncthreads();
    #pragma unroll
    for (int e = 0; e < 8; ++e) {
      Vt[vd + e][vrow]     = (ushort)u0[e];
      Vt[vd + 8 + e][vrow] = (ushort)u1[e];
    }
    __syncthreads();
    if (idx + 1 < nk) {
      const size_t off = (size_t)keep_list[idx+1]*64*N3;
      u0 = *(const bf16x8*)(gv0 + off);
      u1 = *(const bf16x8*)(gv0 + off + 8);
    }
    if (!wave_live) continue;

    #pragma unroll
    for (int jsub = 0; jsub < 2; ++jsub) {
      const int j0s = j0t + jsub*32;
      if (j0s > i0w + 31) continue;
      const float mw = minFF[(b*64 + (j0s >> 5))*64 + (i0w >> 5)];
      if (mw > FFTHR) continue;

      float ffv[16];
      {
        const __half* fft = FFT + (size_t)b*TT*TT + (size_t)j0s*TT + qg;
        #pragma unroll
        for (int r = 0; r < 16; ++r) {
          const int joff = (r&3) + 8*(r>>2) + 4*hi;
          ffv[r] = __half2float(fft[(size_t)joff*TT]);
        }
      }
      f32x16 st;
      #pragma unroll
      for (int r = 0; r < 16; ++r) st[r] = 0.f;
      __builtin_amdgcn_s_setprio(1);         // T5: favor MFMA wave
      #pragma unroll
      for (int dc = 0; dc < 4; ++dc)
        st = __builtin_amdgcn_mfma_f32_32x32x16_bf16(kt[jsub][dc], qf[dc], st, 0, 0, 0);
      __builtin_amdgcn_s_setprio(0);

      float lg[16];
      float pmax = -INFINITY;
      const bool need_mask = (j0s + 31 > i0w);
      #pragma unroll
      for (int r = 0; r < 16; ++r) {
        float v = st[r]*0.125f - ffv[r];
        if (need_mask) {
          const int j = j0s + (r&3) + 8*(r>>2) + 4*hi;
          v = (j <= qg) ? v : -INFINITY;
        }
        lg[r] = v;
        pmax = fmaxf(pmax, v);
      }
      pmax = fmaxf(pmax, __shfl_xor(pmax, 32));
      if (!__all(pmax <= m_run)) {           // T13 defer-max
        const float mn = fmaxf(m_run, pmax);
        const float sc = __expf(m_run - mn);
        m_run = mn;
        l_run *= sc;
        #pragma unroll
        for (int r = 0; r < 16; ++r) {
          const float s0 = __shfl(sc, (r&3) + 8*(r>>2) + 4*hi);
          o0[r] *= s0; o1[r] *= s0;
        }
      }
      float rs = 0.f;
      #pragma unroll
      for (int r = 0; r < 16; ++r) {
        const float pe = __expf(lg[r] - m_run);
        lg[r] = pe;
        rs += pe;
      }
      rs += __shfl_xor(rs, 32);
      l_run += rs;
      uint32_t P8[8], Q8[8];
      #pragma unroll
      for (int g = 0; g < 4; ++g) {
        P8[2*g]   = cvt_pk_bf16(lg[4*g],   lg[4*g+1]);
        P8[2*g+1] = cvt_pk_bf16(lg[4*g+2], lg[4*g+3]);
      }
      #pragma unroll
      for (int k = 0; k < 8; ++k) Q8[k] = (uint32_t)__shfl_xor((int)P8[k], 32);
      __builtin_amdgcn_s_setprio(1);         // T5: favor MFMA wave
      #pragma unroll
      for (int mm = 0; mm < 2; ++mm) {
        pack4_t pk;
        pk.u[0] = hi ? Q8[4*mm+2] : P8[4*mm];
        pk.u[1] = hi ? Q8[4*mm+3] : P8[4*mm+1];
        pk.u[2] = hi ? P8[4*mm+2] : Q8[4*mm];
        pk.u[3] = hi ? P8[4*mm+3] : Q8[4*mm+1];
        const bf16x8 pa = pk.v;
        const bf16x8 v0 = *(const bf16x8*)&Vt[lq]     [jsub*32 + mm*16 + hi*8];
        const bf16x8 v1 = *(const bf16x8*)&Vt[32 + lq][jsub*32 + mm*16 + hi*8];
        o0 = __builtin_amdgcn_mfma_f32_32x32x16_bf16(pa, v0, o0, 0, 0, 0);
        o1 = __builtin_amdgcn_mfma_f32_32x32x16_bf16(pa, v1, o1, 0, 0, 0);
      }
      __builtin_amdgcn_s_setprio(0);
    }
  }
  const float invl = 1.0f / l_run;
  #pragma unroll
  for (int r = 0; r < 16; ++r) {
    const int qm = (r&3) + 8*(r>>2) + 4*hi;
    const float il = __shfl(invl, qm);
    const size_t row = (size_t)(b*TT + i0w + qm)*CC + h*HD;
    Yb[row + lq]      = f2bf(o0[r] * il);
    Yb[row + 32 + lq] = f2bf(o1[r] * il);
  }
}

// ---------------------------------------------------------------------------
extern "C" void kernel_launch(void* const* d_in, const int* in_sizes, int n_in,
                              void* d_out, int out_size, void* d_ws, size_t ws_size,
                              hipStream_t stream) {
  const float* x      = (const float*)d_in[0];
  const float* w_attn = (const float*)d_in[1];
  const float* b_attn = (const float*)d_in[2];
  const float* w_proj = (const float*)d_in[3];
  const float* b_proj = (const float*)d_in[4];
  float* out = (float*)d_out;

  ushort* xb   = (ushort*)d_ws;                         // B*T*C bf16
  ushort* wab  = xb   + (size_t)BB*TT*CC;               // 3C*C bf16
  ushort* wpb  = wab  + (size_t)N3*CC;                  // C*C bf16
  ushort* qkvb = wpb  + (size_t)CC*CC;                  // B*T*3C bf16
  ushort* Yb   = qkvb + (size_t)BB*TT*N3;               // B*T*C bf16
  __half* SFH  = (__half*)(Yb + (size_t)BB*TT*CC);      // B*T*T fp16 (S^T -> FF^T)
  uint32_t* minFFu = (uint32_t*)(SFH + (size_t)BB*TT*TT); // B*64*64 f32-bits

  const int ntot4 = (BB*TT*CC + N3*CC + CC*CC) / 4;
  cast3_k<<<(ntot4 + 255)/256, 256, 0, stream>>>(x, w_attn, w_proj, xb, wab, wpb,
                                                 minFFu);

  gemm_sw<true><<<(N3/128)*((BB*TT)/128), 256, 0, stream>>>(
      xb, wab, b_attn, (void*)qkvb, BB*TT, N3, CC);

  s_scores_T2<<<dim3((NT*(NT+1))/2, BB), 256, 0, stream>>>(qkvb, SFH);
  ff_scan<<<(BB*TT)/4, 256, 0, stream>>>(SFH, minFFu);

  flash_attn7<<<512, 256, 0, stream>>>(qkvb, SFH, (const float*)minFFu, Yb);

  gemm_sw<false><<<(CC/128)*((BB*TT)/128), 256, 0, stream>>>(
      Yb, wpb, b_proj, (void*)out, BB*TT, CC, CC);
}